// Round 1
// baseline (4740.966 us; speedup 1.0000x reference)
//
#include <hip/hip_runtime.h>
#include <cstdint>
#include <cstddef>

#define E_ 8
#define T_ 1024
#define D_ 1024
#define I_ 5632
#define TWO_I_ 11264
#define NG1 8      /* D_/128 */
#define NG2 44     /* I_/128 */
#define NPAIR 2048 /* T_*K */

// workspace layout, units of 4 bytes
#define WS_CNT   0
#define WS_BASE  8
#define WS_ESLOT 16                       /* 2048 ints: t*2+k -> e*1024+slot */
#define WS_TOKW  2064                     /* 2048 floats */
#define WS_ETOK  4112                     /* 8192 ints: e*1024+slot -> token */
#define WS_ACT   12320                    /* NPAIR*I_ floats (46.1 MB) */
#define WS_Y     (12320 + NPAIR * I_)     /* NPAIR*D_ floats (8.4 MB) */

// ---------------------------------------------------------------- routing ---
__global__ void routing_kernel(const float* __restrict__ gate,
                               int* cnt, int* base, int* eslot,
                               float* tokw, int* etok)
{
    int t = threadIdx.x;             // one thread per token, 1024 threads
    if (t < E_) cnt[t] = 0;
    __syncthreads();
    float g[E_];
#pragma unroll
    for (int e = 0; e < E_; ++e) g[e] = gate[t * E_ + e];
    int i0 = 0; float p0 = g[0];
#pragma unroll
    for (int e = 1; e < E_; ++e) if (g[e] > p0) { p0 = g[e]; i0 = e; }
    int i1 = -1; float p1 = -1e30f;
#pragma unroll
    for (int e = 0; e < E_; ++e) if (e != i0 && g[e] > p1) { p1 = g[e]; i1 = e; }
    // renormalized top-2 softmax weights; p1 <= p0 so exp arg <= 0 (stable)
    float w0 = 1.0f / (1.0f + expf(p1 - p0));
    float w1 = 1.0f - w0;
    int s0 = atomicAdd(&cnt[i0], 1);
    int s1 = atomicAdd(&cnt[i1], 1);
    etok[i0 * T_ + s0] = t;
    etok[i1 * T_ + s1] = t;
    eslot[t * 2 + 0] = i0 * T_ + s0;  tokw[t * 2 + 0] = w0;
    eslot[t * 2 + 1] = i1 * T_ + s1;  tokw[t * 2 + 1] = w1;
    __syncthreads();
    if (t == 0) {
        int r = 0;
#pragma unroll
        for (int e = 0; e < E_; ++e) { base[e] = r; r += cnt[e]; }
    }
}

// ------------------------------------------------------- gemm1: x@w1+silu ---
// block: 256 thr = 64 j-lanes x 4 token-groups. tile: 64 tokens x 64 gate ch
// (+64 matching up channels). grid = E_*88*16, token-tile fastest.
__global__ void __launch_bounds__(256) gemm1_kernel(
    const float* __restrict__ x, const int* __restrict__ w1q,
    const float* __restrict__ w1s, const int* __restrict__ cnt,
    const int* __restrict__ base, const int* __restrict__ etok,
    float* __restrict__ act)
{
    int bid = blockIdx.x;
    int tt = bid & 15;
    int jt = (bid >> 4) % 88;
    int e  = bid / (88 * 16);
    int n  = cnt[e];
    int t0 = tt * 64;
    if (t0 >= n) return;
    int nt  = min(64, n - t0);
    int tid = threadIdx.x;
    int jj  = tid & 63;
    int tg  = tid >> 6;
    int j   = jt * 64 + jj;          // gate channel; up channel = I_ + j

    __shared__ float xs[128][64];    // 32 KB, [d][token]

    float accg[16], accu[16];
#pragma unroll
    for (int k = 0; k < 16; ++k) { accg[k] = 0.f; accu[k] = 0.f; }

    const int*   et  = etok + e * T_ + t0;
    const int*   wq  = w1q + (size_t)e * D_ * TWO_I_ + j;
    const float* s1p = w1s + (size_t)e * NG1 * TWO_I_ + j;

    int st = tid & 63;               // staging: token index
    int sd = (tid >> 6) * 32;        // staging: d offset
    int stok = et[st < nt ? st : 0];
    const float* xrow = x + (size_t)stok * D_ + sd;

    for (int g2 = 0; g2 < NG1; ++g2) {
        __syncthreads();
        {
            const float* xr = xrow + g2 * 128;
#pragma unroll
            for (int u = 0; u < 8; ++u) {
                float4 v = *(const float4*)(xr + u * 4);
                int dd = sd + u * 4;
                xs[dd + 0][st] = v.x;
                xs[dd + 1][st] = v.y;
                xs[dd + 2][st] = v.z;
                xs[dd + 3][st] = v.w;
            }
        }
        __syncthreads();
        float sg = s1p[(size_t)g2 * TWO_I_];
        float su = s1p[(size_t)g2 * TWO_I_ + I_];
        const int* wp = wq + (size_t)g2 * 128 * TWO_I_;
#pragma unroll 4
        for (int d = 0; d < 128; ++d) {
            int qg = wp[0];
            int qu = wp[I_];
            wp += TWO_I_;
            float wg = (float)(qg - 8) * sg;   // scale constant over 128-d group
            float wu = (float)(qu - 8) * su;
            const float4* xv = (const float4*)(&xs[d][tg * 16]);
            float xvv[16];
#pragma unroll
            for (int q4 = 0; q4 < 4; ++q4) {
                float4 a = xv[q4];
                xvv[q4 * 4 + 0] = a.x; xvv[q4 * 4 + 1] = a.y;
                xvv[q4 * 4 + 2] = a.z; xvv[q4 * 4 + 3] = a.w;
            }
#pragma unroll
            for (int k = 0; k < 16; ++k) {
                accg[k] += xvv[k] * wg;
                accu[k] += xvv[k] * wu;
            }
        }
    }
    int pbase = base[e] + t0;
#pragma unroll
    for (int k = 0; k < 16; ++k) {
        int trow = tg * 16 + k;
        if (trow < nt) {
            float gg = accg[k];
            float a  = gg / (1.f + expf(-gg)) * accu[k];   // silu(gate)*up
            act[(size_t)(pbase + trow) * I_ + j] = a;
        }
    }
}

// ------------------------------------------------------------ gemm2: act@w2 -
// block: 256 thr = 64 d-lanes x 4 slot-groups. tile: 64 slots x 128 d-cols.
// grid = E_*8*16, slot-tile fastest.
__global__ void __launch_bounds__(256) gemm2_kernel(
    const float* __restrict__ act, const int* __restrict__ w2q,
    const float* __restrict__ w2s, const int* __restrict__ cnt,
    const int* __restrict__ base, float* __restrict__ y)
{
    int bid = blockIdx.x;
    int tt = bid & 15;
    int dt = (bid >> 4) & 7;
    int e  = bid >> 7;
    int n  = cnt[e];
    int t0 = tt * 64;
    if (t0 >= n) return;
    int nt  = min(64, n - t0);
    int tid = threadIdx.x;
    int jj  = tid & 63;
    int tg  = tid >> 6;
    int dcol = dt * 128 + jj;        // second column = dcol + 64

    __shared__ float as_[128][64];   // [i][slot]

    float acc0[16], acc1[16];
#pragma unroll
    for (int k = 0; k < 16; ++k) { acc0[k] = 0.f; acc1[k] = 0.f; }

    int pbase = base[e] + t0;
    int st = tid & 63;
    int si = (tid >> 6) * 32;
    const float* arow = act + (size_t)(pbase + (st < nt ? st : 0)) * I_ + si;
    const int*   wq  = w2q + (size_t)e * I_ * D_ + dcol;
    const float* s2p = w2s + (size_t)e * NG2 * D_ + dcol;

    for (int g2 = 0; g2 < NG2; ++g2) {
        __syncthreads();
        {
            const float* ar = arow + g2 * 128;
#pragma unroll
            for (int u = 0; u < 8; ++u) {
                float4 v = *(const float4*)(ar + u * 4);
                int ii = si + u * 4;
                as_[ii + 0][st] = v.x;
                as_[ii + 1][st] = v.y;
                as_[ii + 2][st] = v.z;
                as_[ii + 3][st] = v.w;
            }
        }
        __syncthreads();
        float sa = s2p[(size_t)g2 * D_];
        float sb = s2p[(size_t)g2 * D_ + 64];
        const int* wp = wq + (size_t)g2 * 128 * D_;
#pragma unroll 4
        for (int i = 0; i < 128; ++i) {
            int qa = wp[0];
            int qb = wp[64];
            wp += D_;
            float wa = (float)(qa - 8) * sa;
            float wb = (float)(qb - 8) * sb;
            const float4* av = (const float4*)(&as_[i][tg * 16]);
            float avv[16];
#pragma unroll
            for (int q4 = 0; q4 < 4; ++q4) {
                float4 a = av[q4];
                avv[q4 * 4 + 0] = a.x; avv[q4 * 4 + 1] = a.y;
                avv[q4 * 4 + 2] = a.z; avv[q4 * 4 + 3] = a.w;
            }
#pragma unroll
            for (int k = 0; k < 16; ++k) {
                acc0[k] += avv[k] * wa;
                acc1[k] += avv[k] * wb;
            }
        }
    }
#pragma unroll
    for (int k = 0; k < 16; ++k) {
        int trow = tg * 16 + k;
        if (trow < nt) {
            y[(size_t)(pbase + trow) * D_ + dcol]      = acc0[k];
            y[(size_t)(pbase + trow) * D_ + dcol + 64] = acc1[k];
        }
    }
}

// --------------------------------------------------------------- combine ---
// out[t,:] = w0 * y[p0,:] + w1 * y[p1,:]   (float4 per thread)
__global__ void combine_kernel(const float* __restrict__ y,
                               const int* __restrict__ eslot,
                               const float* __restrict__ tokw,
                               const int* __restrict__ base,
                               float* __restrict__ out)
{
    int idx = blockIdx.x * blockDim.x + threadIdx.x;  // float4 index, T_*D_/4
    int t  = idx >> 8;                                // 256 float4 per row
    int dc = idx & 255;
    int es0 = eslot[t * 2 + 0], es1 = eslot[t * 2 + 1];
    float w0 = tokw[t * 2 + 0], w1 = tokw[t * 2 + 1];
    int p0 = base[es0 >> 10] + (es0 & 1023);
    int p1 = base[es1 >> 10] + (es1 & 1023);
    const float4* y4 = (const float4*)y;
    float4 a = y4[(size_t)p0 * 256 + dc];
    float4 b = y4[(size_t)p1 * 256 + dc];
    float4 o;
    o.x = w0 * a.x + w1 * b.x;
    o.y = w0 * a.y + w1 * b.y;
    o.z = w0 * a.z + w1 * b.z;
    o.w = w0 * a.w + w1 * b.w;
    ((float4*)out)[idx] = o;
}

// ---------------------------------------------------------------- launch ---
extern "C" void kernel_launch(void* const* d_in, const int* in_sizes, int n_in,
                              void* d_out, int out_size, void* d_ws, size_t ws_size,
                              hipStream_t stream)
{
    const float* x    = (const float*)d_in[0];
    const float* gate = (const float*)d_in[1];
    const int*   w1q  = (const int*)d_in[2];
    const int*   w2q  = (const int*)d_in[3];
    const float* w1s  = (const float*)d_in[4];
    const float* w2s  = (const float*)d_in[5];
    float* out = (float*)d_out;
    int*   wsi = (int*)d_ws;
    float* wsf = (float*)d_ws;

    int*   cnt   = wsi + WS_CNT;
    int*   base  = wsi + WS_BASE;
    int*   eslot = wsi + WS_ESLOT;
    float* tokw  = wsf + WS_TOKW;
    int*   etok  = wsi + WS_ETOK;
    float* act   = wsf + WS_ACT;
    float* y     = wsf + WS_Y;

    routing_kernel<<<1, 1024, 0, stream>>>(gate, cnt, base, eslot, tokw, etok);
    gemm1_kernel<<<E_ * 88 * 16, 256, 0, stream>>>(x, w1q, w1s, cnt, base, etok, act);
    gemm2_kernel<<<E_ * 8 * 16, 256, 0, stream>>>(act, w2q, w2s, cnt, base, y);
    combine_kernel<<<(T_ * D_ / 4) / 256, 256, 0, stream>>>(y, eslot, tokw, base, out);
}

// Round 2
// 1242.367 us; speedup vs baseline: 3.8161x; 3.8161x over previous
//
#include <hip/hip_runtime.h>
#include <cstdint>
#include <cstddef>

#define E_ 8
#define T_ 1024
#define D_ 1024
#define I_ 5632
#define TWO_I_ 11264
#define NG1 8      /* D_/128 */
#define NG2 44     /* I_/128 */

// workspace layout, units of 4 bytes
#define WS_CNT   0
#define WS_BASE  8
#define WS_ESLOT 16
#define WS_TOKW  2064
#define WS_ETOK  4112
#define WS_XG_I  16384                      /* 2048x1024 bf16 = 4 MB   */
#define WS_ACT_I (16384 + 1048576)          /* 2048x5632 bf16 = 23 MB  */
#define WS_Y_I   (16384 + 1048576 + 5767168)/* 2048x1024 f32  = 8 MB   */

typedef __attribute__((ext_vector_type(8))) __bf16 bf16x8;
typedef __attribute__((ext_vector_type(4))) float  f32x4;

__device__ __forceinline__ unsigned short f2bf(float f) {
    unsigned int u = __float_as_uint(f);
    u += 0x7fffu + ((u >> 16) & 1u);        // round-to-nearest-even
    return (unsigned short)(u >> 16);
}

// ---------------------------------------------------------------- routing ---
__global__ void routing_kernel(const float* __restrict__ gate,
                               int* cnt, int* base, int* eslot,
                               float* tokw, int* etok)
{
    int t = threadIdx.x;
    if (t < E_) cnt[t] = 0;
    __syncthreads();
    float g[E_];
#pragma unroll
    for (int e = 0; e < E_; ++e) g[e] = gate[t * E_ + e];
    int i0 = 0; float p0 = g[0];
#pragma unroll
    for (int e = 1; e < E_; ++e) if (g[e] > p0) { p0 = g[e]; i0 = e; }
    int i1 = -1; float p1 = -1e30f;
#pragma unroll
    for (int e = 0; e < E_; ++e) if (e != i0 && g[e] > p1) { p1 = g[e]; i1 = e; }
    float w0 = 1.0f / (1.0f + expf(p1 - p0));
    float w1 = 1.0f - w0;
    int s0 = atomicAdd(&cnt[i0], 1);
    int s1 = atomicAdd(&cnt[i1], 1);
    etok[i0 * T_ + s0] = t;
    etok[i1 * T_ + s1] = t;
    eslot[t * 2 + 0] = i0 * T_ + s0;  tokw[t * 2 + 0] = w0;
    eslot[t * 2 + 1] = i1 * T_ + s1;  tokw[t * 2 + 1] = w1;
    __syncthreads();
    if (t == 0) {
        int r = 0;
#pragma unroll
        for (int e = 0; e < E_; ++e) { base[e] = r; r += cnt[e]; }
    }
}

// ----------------------------------------------- gather x rows, cast bf16 ---
// one block per (e, slot); 256 thr x float4
__global__ void gather_cast_kernel(const float* __restrict__ x,
                                   const int* __restrict__ cnt,
                                   const int* __restrict__ base,
                                   const int* __restrict__ etok,
                                   unsigned short* __restrict__ xg)
{
    int e = blockIdx.x >> 10, slot = blockIdx.x & 1023;
    if (slot >= cnt[e]) return;
    int pair = base[e] + slot;
    int t = etok[e * T_ + slot];
    float4 v = ((const float4*)(x + (size_t)t * D_))[threadIdx.x];
    ushort4 h;
    h.x = f2bf(v.x); h.y = f2bf(v.y); h.z = f2bf(v.z); h.w = f2bf(v.w);
    ((ushort4*)(xg + (size_t)pair * D_))[threadIdx.x] = h;
}

// ------------------------------------------------- gemm1: xg@w1 + silu -----
// tile M=128 pairs x (64 gate + 64 up) cols, BK=32. 4 waves; wave w owns
// 16 gate cols + 16 up cols. In-register dequant -> LDS K-major transpose.
__global__ __launch_bounds__(256, 3) void gemm1_kernel(
    const unsigned short* __restrict__ xg, const int* __restrict__ w1q,
    const float* __restrict__ w1s, const int* __restrict__ cnt,
    const int* __restrict__ base, unsigned short* __restrict__ act)
{
    int bid = blockIdx.x;
    int tt = bid & 7;
    int jt = (bid >> 3) % 88;
    int e  = bid / (8 * 88);
    int n  = cnt[e];
    int t0 = tt * 128;
    if (t0 >= n) return;
    int nt    = min(128, n - t0);
    int pbase = base[e] + t0;
    int tid  = threadIdx.x;
    int lane = tid & 63, w = tid >> 6;
    int l15  = lane & 15, l4 = lane >> 4;
    int j0   = jt * 64;

    __shared__ __align__(16) unsigned short xs[128 * 40];   // A: [m][k] pad 40
    __shared__ __align__(16) unsigned short wsB[128 * 40];  // B: [n][k] pad 40

    f32x4 acc[8][2];
#pragma unroll
    for (int mi = 0; mi < 8; ++mi) {
        acc[mi][0] = (f32x4){0.f, 0.f, 0.f, 0.f};
        acc[mi][1] = (f32x4){0.f, 0.f, 0.f, 0.f};
    }

    // staging roles
    int sa_m = tid >> 1, sa_c = tid & 1;                 // A: 2 thr/row
    int sb_c4 = tid & 31, sb_r4 = tid >> 5;              // B: 32x128 ints
    int cb = sb_c4 * 4;
    int gcol = (cb < 64) ? (j0 + cb) : (I_ + j0 + (cb - 64));
    const int* wbase = w1q + (size_t)e * D_ * TWO_I_ + gcol;
    int sa_row = pbase + min(sa_m, nt - 1);
    const unsigned short* xrow = xg + (size_t)sa_row * D_;

    for (int kg = 0; kg < NG1; ++kg) {
        const float* sp = w1s + ((size_t)e * NG1 + kg) * TWO_I_ + gcol;
        float s_c[4];
#pragma unroll
        for (int cc = 0; cc < 4; ++cc) s_c[cc] = sp[cc];

        for (int ks = 0; ks < 4; ++ks) {
            int k0 = kg * 128 + ks * 32;
            __syncthreads();
            // ---- stage A (128 x 32 bf16)
#pragma unroll
            for (int u = 0; u < 2; ++u) {
                int hq = (sa_c * 2 + u) * 8;
                uint4 v = *(const uint4*)(xrow + k0 + hq);
                *(uint4*)(&xs[sa_m * 40 + hq]) = v;
            }
            // ---- stage B: 4 rows x 4 cols ints, dequant, transpose to [n][k]
            const int* wp = wbase + (size_t)(k0 + sb_r4 * 4) * TWO_I_;
            int4 q0 = *(const int4*)(wp);
            int4 q1 = *(const int4*)(wp + TWO_I_);
            int4 q2 = *(const int4*)(wp + (size_t)2 * TWO_I_);
            int4 q3 = *(const int4*)(wp + (size_t)3 * TWO_I_);
#define PACKCOL1(F, CC) { ushort4 h;                                      \
            h.x = f2bf((float)(q0.F - 8) * s_c[CC]);                      \
            h.y = f2bf((float)(q1.F - 8) * s_c[CC]);                      \
            h.z = f2bf((float)(q2.F - 8) * s_c[CC]);                      \
            h.w = f2bf((float)(q3.F - 8) * s_c[CC]);                      \
            *(ushort4*)(&wsB[(cb + CC) * 40 + sb_r4 * 4]) = h; }
            PACKCOL1(x, 0) PACKCOL1(y, 1) PACKCOL1(z, 2) PACKCOL1(w, 3)
#undef PACKCOL1
            __syncthreads();
            // ---- MFMA
            bf16x8 bg = *(const bf16x8*)(&wsB[(w * 16 + l15) * 40 + l4 * 8]);
            bf16x8 bu = *(const bf16x8*)(&wsB[(64 + w * 16 + l15) * 40 + l4 * 8]);
#pragma unroll
            for (int mi = 0; mi < 8; ++mi) {
                bf16x8 a = *(const bf16x8*)(&xs[(mi * 16 + l15) * 40 + l4 * 8]);
                acc[mi][0] = __builtin_amdgcn_mfma_f32_16x16x32_bf16(a, bg, acc[mi][0], 0, 0, 0);
                acc[mi][1] = __builtin_amdgcn_mfma_f32_16x16x32_bf16(a, bu, acc[mi][1], 0, 0, 0);
            }
        }
    }
    // ---- epilogue: silu(gate)*up -> bf16 act
    int jcol = j0 + w * 16 + l15;
#pragma unroll
    for (int mi = 0; mi < 8; ++mi) {
#pragma unroll
        for (int r = 0; r < 4; ++r) {
            int m = mi * 16 + l4 * 4 + r;
            if (m < nt) {
                float g = acc[mi][0][r], u = acc[mi][1][r];
                float a = g / (1.f + __expf(-g)) * u;
                act[(size_t)(pbase + m) * I_ + jcol] = f2bf(a);
            }
        }
    }
}

// ---------------------------------------------------- gemm2: act@w2 --------
// tile M=64 x N=64 dcols, BK=64. 4 waves; wave w owns 16 cols.
__global__ __launch_bounds__(256, 3) void gemm2_kernel(
    const unsigned short* __restrict__ act, const int* __restrict__ w2q,
    const float* __restrict__ w2s, const int* __restrict__ cnt,
    const int* __restrict__ base, float* __restrict__ y)
{
    int bid = blockIdx.x;
    int tt = bid & 15;
    int dt = (bid >> 4) & 15;
    int e  = bid >> 8;
    int n  = cnt[e];
    int t0 = tt * 64;
    if (t0 >= n) return;
    int nt    = min(64, n - t0);
    int pbase = base[e] + t0;
    int tid  = threadIdx.x;
    int lane = tid & 63, w = tid >> 6;
    int l15  = lane & 15, l4 = lane >> 4;
    int d0   = dt * 64;

    __shared__ __align__(16) unsigned short as2[64 * 72];   // A: [m][k] pad 72
    __shared__ __align__(16) unsigned short wt2[64 * 72];   // B: [n][k] pad 72

    f32x4 acc[4];
#pragma unroll
    for (int mi = 0; mi < 4; ++mi) acc[mi] = (f32x4){0.f, 0.f, 0.f, 0.f};

    int sa_m = tid >> 2, sa_c = tid & 3;                 // A: 4 thr/row
    int sa_row = pbase + min(sa_m, nt - 1);
    const unsigned short* arow = act + (size_t)sa_row * I_;
    int sb_c4 = tid & 15, sb_r4 = tid >> 4;              // B: 64x64 ints
    int cb = sb_c4 * 4;
    const int*   wbase = w2q + (size_t)e * I_ * D_ + d0 + cb;
    const float* sbase = w2s + (size_t)e * NG2 * D_ + d0 + cb;

    float s_c[4] = {0.f, 0.f, 0.f, 0.f};
    for (int ks = 0; ks < 88; ++ks) {
        int k0 = ks * 64;
        if ((k0 & 127) == 0) {
            int g = k0 >> 7;
#pragma unroll
            for (int cc = 0; cc < 4; ++cc) s_c[cc] = sbase[(size_t)g * D_ + cc];
        }
        __syncthreads();
        // ---- stage A (64 x 64 bf16)
#pragma unroll
        for (int u = 0; u < 2; ++u) {
            int hq = (sa_c * 2 + u) * 8;
            uint4 v = *(const uint4*)(arow + k0 + hq);
            *(uint4*)(&as2[sa_m * 72 + hq]) = v;
        }
        // ---- stage B
        const int* wp = wbase + (size_t)(k0 + sb_r4 * 4) * D_;
        int4 q0 = *(const int4*)(wp);
        int4 q1 = *(const int4*)(wp + D_);
        int4 q2 = *(const int4*)(wp + (size_t)2 * D_);
        int4 q3 = *(const int4*)(wp + (size_t)3 * D_);
#define PACKCOL2(F, CC) { ushort4 h;                                      \
        h.x = f2bf((float)(q0.F - 8) * s_c[CC]);                          \
        h.y = f2bf((float)(q1.F - 8) * s_c[CC]);                          \
        h.z = f2bf((float)(q2.F - 8) * s_c[CC]);                          \
        h.w = f2bf((float)(q3.F - 8) * s_c[CC]);                          \
        *(ushort4*)(&wt2[(cb + CC) * 72 + sb_r4 * 4]) = h; }
        PACKCOL2(x, 0) PACKCOL2(y, 1) PACKCOL2(z, 2) PACKCOL2(w, 3)
#undef PACKCOL2
        __syncthreads();
        // ---- MFMA (two K=32 halves)
#pragma unroll
        for (int kh = 0; kh < 2; ++kh) {
            bf16x8 b = *(const bf16x8*)(&wt2[(w * 16 + l15) * 72 + kh * 32 + l4 * 8]);
#pragma unroll
            for (int mi = 0; mi < 4; ++mi) {
                bf16x8 a = *(const bf16x8*)(&as2[(mi * 16 + l15) * 72 + kh * 32 + l4 * 8]);
                acc[mi] = __builtin_amdgcn_mfma_f32_16x16x32_bf16(a, b, acc[mi], 0, 0, 0);
            }
        }
    }
    int dcol = d0 + w * 16 + l15;
#pragma unroll
    for (int mi = 0; mi < 4; ++mi) {
#pragma unroll
        for (int r = 0; r < 4; ++r) {
            int m = mi * 16 + l4 * 4 + r;
            if (m < nt) y[(size_t)(pbase + m) * D_ + dcol] = acc[mi][r];
        }
    }
}

// --------------------------------------------------------------- combine ---
__global__ void combine_kernel(const float* __restrict__ y,
                               const int* __restrict__ eslot,
                               const float* __restrict__ tokw,
                               const int* __restrict__ base,
                               float* __restrict__ out)
{
    int idx = blockIdx.x * blockDim.x + threadIdx.x;
    int t  = idx >> 8;
    int dc = idx & 255;
    int es0 = eslot[t * 2 + 0], es1 = eslot[t * 2 + 1];
    float w0 = tokw[t * 2 + 0], w1 = tokw[t * 2 + 1];
    int p0 = base[es0 >> 10] + (es0 & 1023);
    int p1 = base[es1 >> 10] + (es1 & 1023);
    const float4* y4 = (const float4*)y;
    float4 a = y4[(size_t)p0 * 256 + dc];
    float4 b = y4[(size_t)p1 * 256 + dc];
    float4 o;
    o.x = w0 * a.x + w1 * b.x;
    o.y = w0 * a.y + w1 * b.y;
    o.z = w0 * a.z + w1 * b.z;
    o.w = w0 * a.w + w1 * b.w;
    ((float4*)out)[idx] = o;
}

// ---------------------------------------------------------------- launch ---
extern "C" void kernel_launch(void* const* d_in, const int* in_sizes, int n_in,
                              void* d_out, int out_size, void* d_ws, size_t ws_size,
                              hipStream_t stream)
{
    const float* x    = (const float*)d_in[0];
    const float* gate = (const float*)d_in[1];
    const int*   w1q  = (const int*)d_in[2];
    const int*   w2q  = (const int*)d_in[3];
    const float* w1s  = (const float*)d_in[4];
    const float* w2s  = (const float*)d_in[5];
    float* out = (float*)d_out;
    int*   wsi = (int*)d_ws;
    float* wsf = (float*)d_ws;

    int*   cnt   = wsi + WS_CNT;
    int*   base  = wsi + WS_BASE;
    int*   eslot = wsi + WS_ESLOT;
    float* tokw  = wsf + WS_TOKW;
    int*   etok  = wsi + WS_ETOK;
    unsigned short* xg  = (unsigned short*)(wsi + WS_XG_I);
    unsigned short* act = (unsigned short*)(wsi + WS_ACT_I);
    float*          y   = wsf + WS_Y_I;

    routing_kernel<<<1, 1024, 0, stream>>>(gate, cnt, base, eslot, tokw, etok);
    gather_cast_kernel<<<E_ * T_, 256, 0, stream>>>(x, cnt, base, etok, xg);
    gemm1_kernel<<<E_ * 88 * 8, 256, 0, stream>>>(xg, w1q, w1s, cnt, base, act);
    gemm2_kernel<<<E_ * 16 * 16, 256, 0, stream>>>(act, w2q, w2s, cnt, base, y);
    combine_kernel<<<(T_ * D_ / 4) / 256, 256, 0, stream>>>(y, eslot, tokw, base, out);
}

// Round 3
// 1092.462 us; speedup vs baseline: 4.3397x; 1.1372x over previous
//
#include <hip/hip_runtime.h>
#include <cstdint>
#include <cstddef>

#define E_ 8
#define T_ 1024
#define D_ 1024
#define I_ 5632
#define TWO_I_ 11264
#define NPAIR 2048

// workspace layout, units of 4 bytes
#define WS_CNT   0
#define WS_BASE  8
#define WS_ESLOT 16
#define WS_TOKW  2064
#define WS_ETOK  4112
#define WS_XG_I  16384                                /* 2048x1024 bf16 = 4 MB  */
#define WS_ACT_I (WS_XG_I + (NPAIR * D_ / 2))         /* 2048x5632 bf16 = 23 MB */
#define WS_Y_I   (WS_ACT_I + (NPAIR * I_ / 2))        /* 2 x 2048x1024 f32      */

typedef __attribute__((ext_vector_type(8))) __bf16 bf16x8;
typedef __attribute__((ext_vector_type(4))) float  f32x4;

__device__ __forceinline__ unsigned f2bf(float f) {
    unsigned u = __float_as_uint(f);
    u += 0x7fffu + ((u >> 16) & 1u);
    return u >> 16;
}
__device__ __forceinline__ unsigned pack2bf(float f0, float f1) {
    unsigned a0 = __float_as_uint(f0); a0 += 0x7fffu + ((a0 >> 16) & 1u);
    unsigned a1 = __float_as_uint(f1); a1 += 0x7fffu + ((a1 >> 16) & 1u);
    return (a0 >> 16) | (a1 & 0xffff0000u);
}
// async global->LDS, 16 B per lane; lds base must be wave-uniform
__device__ __forceinline__ void gl_lds16(const void* g, void* l) {
    __builtin_amdgcn_global_load_lds(
        (const __attribute__((address_space(1))) unsigned int*)g,
        (__attribute__((address_space(3))) unsigned int*)l, 16, 0, 0);
}

// ---------------------------------------------------------------- routing ---
__global__ void routing_kernel(const float* __restrict__ gate,
                               int* cnt, int* base, int* eslot,
                               float* tokw, int* etok)
{
    int t = threadIdx.x;
    if (t < E_) cnt[t] = 0;
    __syncthreads();
    float g[E_];
#pragma unroll
    for (int e = 0; e < E_; ++e) g[e] = gate[t * E_ + e];
    int i0 = 0; float p0 = g[0];
#pragma unroll
    for (int e = 1; e < E_; ++e) if (g[e] > p0) { p0 = g[e]; i0 = e; }
    int i1 = -1; float p1 = -1e30f;
#pragma unroll
    for (int e = 0; e < E_; ++e) if (e != i0 && g[e] > p1) { p1 = g[e]; i1 = e; }
    float w0 = 1.0f / (1.0f + expf(p1 - p0));
    float w1 = 1.0f - w0;
    int s0 = atomicAdd(&cnt[i0], 1);
    int s1 = atomicAdd(&cnt[i1], 1);
    etok[i0 * T_ + s0] = t;
    etok[i1 * T_ + s1] = t;
    eslot[t * 2 + 0] = i0 * T_ + s0;  tokw[t * 2 + 0] = w0;
    eslot[t * 2 + 1] = i1 * T_ + s1;  tokw[t * 2 + 1] = w1;
    __syncthreads();
    if (t == 0) {
        int r = 0;
#pragma unroll
        for (int e = 0; e < E_; ++e) { base[e] = r; r += cnt[e]; }
    }
}

// ----------------------------------------------- gather x rows, cast bf16 ---
__global__ void gather_cast_kernel(const float* __restrict__ x,
                                   const int* __restrict__ cnt,
                                   const int* __restrict__ base,
                                   const int* __restrict__ etok,
                                   unsigned short* __restrict__ xg)
{
    int e = blockIdx.x >> 10, slot = blockIdx.x & 1023;
    if (slot >= cnt[e]) return;
    int pair = base[e] + slot;
    int t = etok[e * T_ + slot];
    float4 v = ((const float4*)(x + (size_t)t * D_))[threadIdx.x];
    ushort4 h;
    h.x = (unsigned short)f2bf(v.x); h.y = (unsigned short)f2bf(v.y);
    h.z = (unsigned short)f2bf(v.z); h.w = (unsigned short)f2bf(v.w);
    ((ushort4*)(xg + (size_t)pair * D_))[threadIdx.x] = h;
}

// ------------------------------------------------- gemm1: xg@w1 + silu -----
// grid = E_*176. Block: 32 gate cols (cg*32..+31) + matching up cols, M=384
// (mg loop for n>384), K=1024, BK=32. 4 waves = 2 col-16-groups x 2 m-halves.
// Weights: per-lane direct global loads + in-reg dequant (read ONCE per elem).
// A: async global_load_lds, chunk-interleaved layout, double-buffered.
__global__ __launch_bounds__(256, 3) void gemm1_kernel(
    const unsigned short* __restrict__ xg, const int* __restrict__ w1q,
    const float* __restrict__ w1s, const int* __restrict__ cnt,
    const int* __restrict__ base, unsigned short* __restrict__ act)
{
    int bid = blockIdx.x;
    int cg = bid % 176, e = bid / 176;
    int n = cnt[e];
    if (n <= 0) return;
    int pbase = base[e];
    int tid = threadIdx.x, lane = tid & 63, w = tid >> 6;
    int l15 = lane & 15, lq = lane >> 4;
    int colg = w & 1, mh = w >> 1;
    int jcol = cg * 32 + colg * 16 + l15;     // gate col; up col = jcol + I_

    __shared__ __align__(16) char bufA[2][24576];   // 2 x 384x32 bf16

    for (int mg = 0; mg * 384 < n; ++mg) {
        int tb = mg * 384;
        // A staging pointers: wave stages 16-row groups w*6..w*6+5;
        // lane -> row (lane&15), k-chunk (lane>>4)*8 shorts
        const char* ap[6];
#pragma unroll
        for (int g = 0; g < 6; ++g) {
            int row = tb + (w * 6 + g) * 16 + l15;
            row = row < n ? row : n - 1;
            ap[g] = (const char*)xg + (size_t)(pbase + row) * 2048 + lq * 16;
        }
        // B per-lane pointers: k = t*32 + lq*8 + j
        const char* bg = (const char*)w1q +
            ((size_t)(e * 1024 + lq * 8) * TWO_I_ + jcol) * 4;
        const char* bu = bg + (size_t)I_ * 4;

        f32x4 accg[12], accu[12];
#pragma unroll
        for (int mi = 0; mi < 12; ++mi) {
            accg[mi] = (f32x4){0.f, 0.f, 0.f, 0.f};
            accu[mi] = (f32x4){0.f, 0.f, 0.f, 0.f};
        }
        int q_g[8], q_u[8];

        // prologue: stage t=0 (A -> buf0, B -> regs)
#pragma unroll
        for (int g = 0; g < 6; ++g) {
            gl_lds16(ap[g], (char*)bufA[0] + (w * 6 + g) * 1024);
            ap[g] += 64;
        }
#pragma unroll
        for (int j = 0; j < 8; ++j) {
            q_g[j] = *(const int*)(bg + (size_t)j * (TWO_I_ * 4));
            q_u[j] = *(const int*)(bu + (size_t)j * (TWO_I_ * 4));
        }
        bg += (size_t)32 * TWO_I_ * 4;
        bu += (size_t)32 * TWO_I_ * 4;
        __syncthreads();

        for (int kg = 0; kg < 8; ++kg) {
            const float* sp = w1s + ((size_t)e * 8 + kg) * TWO_I_ + jcol;
            float sg = sp[0], su = sp[I_];
            float og = -8.f * sg, ou = -8.f * su;
#pragma unroll
            for (int ks = 0; ks < 4; ++ks) {
                const int p = ks & 1;
                // dequant current q -> bf16 fragments
                union { unsigned u[4]; bf16x8 v; } fg, fu;
#pragma unroll
                for (int h = 0; h < 4; ++h) {
                    fg.u[h] = pack2bf((float)q_g[2*h] * sg + og,
                                      (float)q_g[2*h+1] * sg + og);
                    fu.u[h] = pack2bf((float)q_u[2*h] * su + ou,
                                      (float)q_u[2*h+1] * su + ou);
                }
                // prefetch next step (B regs + A DMA into other buffer)
                if (!(kg == 7 && ks == 3)) {
#pragma unroll
                    for (int j = 0; j < 8; ++j) {
                        q_g[j] = *(const int*)(bg + (size_t)j * (TWO_I_ * 4));
                        q_u[j] = *(const int*)(bu + (size_t)j * (TWO_I_ * 4));
                    }
                    bg += (size_t)32 * TWO_I_ * 4;
                    bu += (size_t)32 * TWO_I_ * 4;
#pragma unroll
                    for (int g = 0; g < 6; ++g) {
                        gl_lds16(ap[g], (char*)bufA[p ^ 1] + (w * 6 + g) * 1024);
                        ap[g] += 64;
                    }
                }
                // MFMA over this wave's 192-row half
                const char* pa = (const char*)bufA[p] + mh * 12288
                               + lq * 256 + l15 * 16;
#pragma unroll
                for (int mi = 0; mi < 12; ++mi) {
                    bf16x8 a = *(const bf16x8*)(pa + mi * 1024);
                    accg[mi] = __builtin_amdgcn_mfma_f32_16x16x32_bf16(a, fg.v, accg[mi], 0, 0, 0);
                    accu[mi] = __builtin_amdgcn_mfma_f32_16x16x32_bf16(a, fu.v, accu[mi], 0, 0, 0);
                }
                __syncthreads();
            }
        }
        // epilogue: silu(gate)*up -> bf16
#pragma unroll
        for (int mi = 0; mi < 12; ++mi) {
#pragma unroll
            for (int r = 0; r < 4; ++r) {
                int m = tb + mh * 192 + mi * 16 + lq * 4 + r;
                if (m < n) {
                    float gv = accg[mi][r], uv = accu[mi][r];
                    float a = gv / (1.f + __expf(-gv)) * uv;
                    act[(size_t)(pbase + m) * I_ + jcol] = (unsigned short)f2bf(a);
                }
            }
        }
    }
}

// ---------------------------------------------------- gemm2: act@w2 --------
// grid = E_*16*2: e, dt (64 d-cols), seg (K halves of 2816). M=384 (mg loop),
// BK=32, 88 K-steps. 4 waves = 2 col-32-groups x 2 m-halves; wave owns 2
// 16-col fragments. Partial sums to y[seg]; combine adds the 2 segments.
__global__ __launch_bounds__(256, 3) void gemm2_kernel(
    const unsigned short* __restrict__ act, const int* __restrict__ w2q,
    const float* __restrict__ w2s, const int* __restrict__ cnt,
    const int* __restrict__ base, float* __restrict__ y)
{
    int bid = blockIdx.x;
    int seg = bid & 1, dt = (bid >> 1) & 15, e = bid >> 5;
    int n = cnt[e];
    if (n <= 0) return;
    int pbase = base[e];
    int tid = threadIdx.x, lane = tid & 63, w = tid >> 6;
    int l15 = lane & 15, lq = lane >> 4;
    int colg = w & 1, mh = w >> 1;
    int dcol0 = dt * 64 + colg * 32 + l15;    // second frag col = dcol0 + 16

    __shared__ __align__(16) char bufA[2][24576];

    float* yseg = y + (size_t)seg * NPAIR * D_;

    for (int mg = 0; mg * 384 < n; ++mg) {
        int tb = mg * 384;
        const char* ap[6];
#pragma unroll
        for (int g = 0; g < 6; ++g) {
            int row = tb + (w * 6 + g) * 16 + l15;
            row = row < n ? row : n - 1;
            ap[g] = (const char*)act + (size_t)(pbase + row) * (I_ * 2)
                  + seg * 5632 + lq * 16;
        }
        const char* b0 = (const char*)w2q +
            ((size_t)(e * 5632 + seg * 2816 + lq * 8) * D_ + dcol0) * 4;
        const char* b1 = b0 + 64;

        f32x4 acc0[12], acc1[12];
#pragma unroll
        for (int mi = 0; mi < 12; ++mi) {
            acc0[mi] = (f32x4){0.f, 0.f, 0.f, 0.f};
            acc1[mi] = (f32x4){0.f, 0.f, 0.f, 0.f};
        }
        int q_0[8], q_1[8];

#pragma unroll
        for (int g = 0; g < 6; ++g) {
            gl_lds16(ap[g], (char*)bufA[0] + (w * 6 + g) * 1024);
            ap[g] += 64;
        }
#pragma unroll
        for (int j = 0; j < 8; ++j) {
            q_0[j] = *(const int*)(b0 + (size_t)j * (D_ * 4));
            q_1[j] = *(const int*)(b1 + (size_t)j * (D_ * 4));
        }
        b0 += (size_t)32 * D_ * 4;
        b1 += (size_t)32 * D_ * 4;
        __syncthreads();

        for (int kgl = 0; kgl < 22; ++kgl) {
            const float* sp = w2s + ((size_t)e * 44 + seg * 22 + kgl) * D_ + dcol0;
            float s0 = sp[0], s1 = sp[16];
            float o0 = -8.f * s0, o1 = -8.f * s1;
#pragma unroll
            for (int ks = 0; ks < 4; ++ks) {
                const int p = ks & 1;
                union { unsigned u[4]; bf16x8 v; } f0, f1;
#pragma unroll
                for (int h = 0; h < 4; ++h) {
                    f0.u[h] = pack2bf((float)q_0[2*h] * s0 + o0,
                                      (float)q_0[2*h+1] * s0 + o0);
                    f1.u[h] = pack2bf((float)q_1[2*h] * s1 + o1,
                                      (float)q_1[2*h+1] * s1 + o1);
                }
                if (!(kgl == 21 && ks == 3)) {
#pragma unroll
                    for (int j = 0; j < 8; ++j) {
                        q_0[j] = *(const int*)(b0 + (size_t)j * (D_ * 4));
                        q_1[j] = *(const int*)(b1 + (size_t)j * (D_ * 4));
                    }
                    b0 += (size_t)32 * D_ * 4;
                    b1 += (size_t)32 * D_ * 4;
#pragma unroll
                    for (int g = 0; g < 6; ++g) {
                        gl_lds16(ap[g], (char*)bufA[p ^ 1] + (w * 6 + g) * 1024);
                        ap[g] += 64;
                    }
                }
                const char* pa = (const char*)bufA[p] + mh * 12288
                               + lq * 256 + l15 * 16;
#pragma unroll
                for (int mi = 0; mi < 12; ++mi) {
                    bf16x8 a = *(const bf16x8*)(pa + mi * 1024);
                    acc0[mi] = __builtin_amdgcn_mfma_f32_16x16x32_bf16(a, f0.v, acc0[mi], 0, 0, 0);
                    acc1[mi] = __builtin_amdgcn_mfma_f32_16x16x32_bf16(a, f1.v, acc1[mi], 0, 0, 0);
                }
                __syncthreads();
            }
        }
#pragma unroll
        for (int mi = 0; mi < 12; ++mi) {
#pragma unroll
            for (int r = 0; r < 4; ++r) {
                int m = tb + mh * 192 + mi * 16 + lq * 4 + r;
                if (m < n) {
                    float* yr = yseg + (size_t)(pbase + m) * D_;
                    yr[dcol0]      = acc0[mi][r];
                    yr[dcol0 + 16] = acc1[mi][r];
                }
            }
        }
    }
}

// --------------------------------------------------------------- combine ---
__global__ void combine_kernel(const float* __restrict__ y,
                               const int* __restrict__ eslot,
                               const float* __restrict__ tokw,
                               const int* __restrict__ base,
                               float* __restrict__ out)
{
    int idx = blockIdx.x * blockDim.x + threadIdx.x;
    int t  = idx >> 8;
    int dc = idx & 255;
    int es0 = eslot[t * 2 + 0], es1 = eslot[t * 2 + 1];
    float w0 = tokw[t * 2 + 0], w1 = tokw[t * 2 + 1];
    int p0 = base[es0 >> 10] + (es0 & 1023);
    int p1 = base[es1 >> 10] + (es1 & 1023);
    const float4* y4 = (const float4*)y;
    float4 a0 = y4[(size_t)p0 * 256 + dc];
    float4 a1 = y4[(size_t)(NPAIR + p0) * 256 + dc];
    float4 b0 = y4[(size_t)p1 * 256 + dc];
    float4 b1 = y4[(size_t)(NPAIR + p1) * 256 + dc];
    float4 o;
    o.x = w0 * (a0.x + a1.x) + w1 * (b0.x + b1.x);
    o.y = w0 * (a0.y + a1.y) + w1 * (b0.y + b1.y);
    o.z = w0 * (a0.z + a1.z) + w1 * (b0.z + b1.z);
    o.w = w0 * (a0.w + a1.w) + w1 * (b0.w + b1.w);
    ((float4*)out)[idx] = o;
}

// ---------------------------------------------------------------- launch ---
extern "C" void kernel_launch(void* const* d_in, const int* in_sizes, int n_in,
                              void* d_out, int out_size, void* d_ws, size_t ws_size,
                              hipStream_t stream)
{
    const float* x    = (const float*)d_in[0];
    const float* gate = (const float*)d_in[1];
    const int*   w1q  = (const int*)d_in[2];
    const int*   w2q  = (const int*)d_in[3];
    const float* w1s  = (const float*)d_in[4];
    const float* w2s  = (const float*)d_in[5];
    float* out = (float*)d_out;
    int*   wsi = (int*)d_ws;
    float* wsf = (float*)d_ws;

    int*   cnt   = wsi + WS_CNT;
    int*   base  = wsi + WS_BASE;
    int*   eslot = wsi + WS_ESLOT;
    float* tokw  = wsf + WS_TOKW;
    int*   etok  = wsi + WS_ETOK;
    unsigned short* xg  = (unsigned short*)(wsi + WS_XG_I);
    unsigned short* act = (unsigned short*)(wsi + WS_ACT_I);
    float*          y   = wsf + WS_Y_I;

    routing_kernel<<<1, 1024, 0, stream>>>(gate, cnt, base, eslot, tokw, etok);
    gather_cast_kernel<<<E_ * T_, 256, 0, stream>>>(x, cnt, base, etok, xg);
    gemm1_kernel<<<E_ * 176, 256, 0, stream>>>(xg, w1q, w1s, cnt, base, act);
    gemm2_kernel<<<E_ * 16 * 2, 256, 0, stream>>>(act, w2q, w2s, cnt, base, y);
    combine_kernel<<<(T_ * D_ / 4) / 256, 256, 0, stream>>>(y, eslot, tokw, base, out);
}

// Round 4
// 843.458 us; speedup vs baseline: 5.6209x; 1.2952x over previous
//
#include <hip/hip_runtime.h>
#include <cstdint>
#include <cstddef>

#define E_ 8
#define T_ 1024
#define D_ 1024
#define I_ 5632
#define TWO_I_ 11264
#define NPAD_MAX 2176                 /* 2048 + 8*16 */
#define NGRP_MAX 136

// ws layout (bytes): int tables in [0,64K), then act_f, then xg_f, y overlays xg_f
#define WS_ACTF_B 65536
#define WS_XGF_B  (65536 + 24510464)              /* act_f = 136*180224      */
#define WS_Y_B    WS_XGF_B                        /* y overlays dead xg_f    */
// int-table offsets (units of 4 B)
#define WS_CNT   0
#define WS_BASEP 8
#define WS_ESLOT 16
#define WS_TOKW  2064
#define WS_ETOK  4112

typedef __attribute__((ext_vector_type(8))) __bf16 bf16x8;
typedef __attribute__((ext_vector_type(4))) float  f32x4;

__device__ __forceinline__ unsigned f2bf(float f) {
    unsigned u = __float_as_uint(f);
    u += 0x7fffu + ((u >> 16) & 1u);
    return u >> 16;
}
__device__ __forceinline__ unsigned pack2bf(float f0, float f1) {
    unsigned a0 = __float_as_uint(f0); a0 += 0x7fffu + ((a0 >> 16) & 1u);
    unsigned a1 = __float_as_uint(f1); a1 += 0x7fffu + ((a1 >> 16) & 1u);
    return (a0 >> 16) | (a1 & 0xffff0000u);
}

// ---------------------------------------------------------------- routing ---
__global__ void routing_kernel(const float* __restrict__ gate,
                               int* cnt, int* basep, int* eslot,
                               float* tokw, int* etok)
{
    int t = threadIdx.x;
    if (t < E_) cnt[t] = 0;
    __syncthreads();
    float g[E_];
#pragma unroll
    for (int e = 0; e < E_; ++e) g[e] = gate[t * E_ + e];
    int i0 = 0; float p0 = g[0];
#pragma unroll
    for (int e = 1; e < E_; ++e) if (g[e] > p0) { p0 = g[e]; i0 = e; }
    int i1 = -1; float p1 = -1e30f;
#pragma unroll
    for (int e = 0; e < E_; ++e) if (e != i0 && g[e] > p1) { p1 = g[e]; i1 = e; }
    float w0 = 1.0f / (1.0f + expf(p1 - p0));
    float w1 = 1.0f - w0;
    int s0 = atomicAdd(&cnt[i0], 1);
    int s1 = atomicAdd(&cnt[i1], 1);
    etok[i0 * T_ + s0] = t;
    etok[i1 * T_ + s1] = t;
    eslot[t * 2 + 0] = i0 * T_ + s0;  tokw[t * 2 + 0] = w0;
    eslot[t * 2 + 1] = i1 * T_ + s1;  tokw[t * 2 + 1] = w1;
    __syncthreads();
    if (t == 0) {
        int r = 0;
#pragma unroll
        for (int e = 0; e < E_; ++e) { basep[e] = r; r += (cnt[e] + 15) & ~15; }
    }
}

// ------------------- gather x rows, cast bf16, fragment-major swizzle -------
// xg_f[grp][kchunk=k/8][row16][k%8]; grp = padded_pair/16. One block per
// (e, 16-row grp): 256 thr x 8 iters, 16-B stores contiguous.
__global__ void gather_cast_kernel(const float* __restrict__ x,
                                   const int* __restrict__ cnt,
                                   const int* __restrict__ basep,
                                   const int* __restrict__ etok,
                                   unsigned short* __restrict__ xgf)
{
    int e = blockIdx.x >> 6, g = blockIdx.x & 63;
    int n = cnt[e];
    if (g * 16 >= n) return;
    int tid = threadIdx.x;
    int row = g * 16 + (tid & 15);
    row = min(row, n - 1);
    int tok = etok[e * T_ + row];
    const float* xr = x + (size_t)tok * D_;
    unsigned short* dst = xgf + ((size_t)(basep[e] >> 4) + g) * 16384;
#pragma unroll
    for (int it = 0; it < 8; ++it) {
        int c = it * 16 + (tid >> 4);          // k-chunk 0..127
        float4 v0 = *(const float4*)(xr + c * 8);
        float4 v1 = *(const float4*)(xr + c * 8 + 4);
        uint4 h;
        h.x = pack2bf(v0.x, v0.y); h.y = pack2bf(v0.z, v0.w);
        h.z = pack2bf(v1.x, v1.y); h.w = pack2bf(v1.z, v1.w);
        *(uint4*)(dst + c * 128 + (tid & 15) * 8) = h;
    }
}

// ------------------------------------------------- gemm1: xg@w1 + silu -----
// grid = E_*176. Block 4 waves (colg, mh), NO LDS, NO barriers. Wave tile:
// M=160 (10 frags) x (16 gate + 16 up). A: coalesced 1-KB frag loads from
// xg_f. B: per-lane q loads, in-reg dequant, ping-pong prefetch.
__global__ __launch_bounds__(256, 2) void gemm1_kernel(
    const unsigned short* __restrict__ xgf, const int* __restrict__ w1q,
    const float* __restrict__ w1s, const int* __restrict__ cnt,
    const int* __restrict__ basep, unsigned short* __restrict__ actf)
{
    int cg = blockIdx.x % 176, e = blockIdx.x / 176;
    int n = cnt[e];
    if (n <= 0) return;
    int npad = (n + 15) & ~15;
    int pb = basep[e];
    int tid = threadIdx.x, lane = tid & 63, w = tid >> 6;
    int l15 = lane & 15, lq = lane >> 4;
    int colg = w & 1, mh = w >> 1;
    int jcol = cg * 32 + colg * 16 + l15;

    const char* bg0 = (const char*)(w1q + ((size_t)e * 1024 + lq * 8) * TWO_I_ + jcol);
    const char* bu0 = bg0 + (size_t)I_ * 4;

    for (int tb = 0; tb < npad; tb += 320) {
        int aoff[10];
#pragma unroll
        for (int mi = 0; mi < 10; ++mi) {
            int R = tb + mh * 160 + mi * 16;
            R = min(R, npad - 16);
            aoff[mi] = ((pb + R) >> 4) * 32768;
        }
        const char* abase = (const char*)xgf + lq * 256 + l15 * 16;
        const char* bg = bg0;
        const char* bu = bu0;

        f32x4 accg[10], accu[10];
#pragma unroll
        for (int mi = 0; mi < 10; ++mi) {
            accg[mi] = (f32x4){0.f, 0.f, 0.f, 0.f};
            accu[mi] = (f32x4){0.f, 0.f, 0.f, 0.f};
        }
        int qg[2][8], qu[2][8];
#pragma unroll
        for (int j = 0; j < 8; ++j) {
            qg[0][j] = *(const int*)(bg + (size_t)j * 45056);
            qu[0][j] = *(const int*)(bu + (size_t)j * 45056);
        }
        bg += 1441792; bu += 1441792;          // 32*TWO_I_*4
        float sg = 0.f, su = 0.f, og = 0.f, ou = 0.f;

#pragma unroll 4
        for (int t = 0; t < 32; ++t) {
            const int cur = t & 1;
            if ((t & 3) == 0) {
                const float* sp = w1s + ((size_t)e * 8 + (t >> 2)) * TWO_I_ + jcol;
                sg = sp[0]; su = sp[I_];
                og = -8.f * sg; ou = -8.f * su;
            }
            // A fragment loads (coalesced 1 KB per instruction)
            const char* at = abase + t * 1024;
            bf16x8 a[10];
#pragma unroll
            for (int mi = 0; mi < 10; ++mi)
                a[mi] = *(const bf16x8*)(at + aoff[mi]);
            // dequant current B
            union { unsigned u[4]; bf16x8 v; } fg, fu;
#pragma unroll
            for (int h = 0; h < 4; ++h) {
                fg.u[h] = pack2bf((float)qg[cur][2*h] * sg + og,
                                  (float)qg[cur][2*h+1] * sg + og);
                fu.u[h] = pack2bf((float)qu[cur][2*h] * su + ou,
                                  (float)qu[cur][2*h+1] * su + ou);
            }
            // prefetch next B (stays in flight a whole step - no barriers)
            if (t < 31) {
#pragma unroll
                for (int j = 0; j < 8; ++j) {
                    qg[cur ^ 1][j] = *(const int*)(bg + (size_t)j * 45056);
                    qu[cur ^ 1][j] = *(const int*)(bu + (size_t)j * 45056);
                }
                bg += 1441792; bu += 1441792;
            }
#pragma unroll
            for (int mi = 0; mi < 10; ++mi) {
                accg[mi] = __builtin_amdgcn_mfma_f32_16x16x32_bf16(a[mi], fg.v, accg[mi], 0, 0, 0);
                accu[mi] = __builtin_amdgcn_mfma_f32_16x16x32_bf16(a[mi], fu.v, accu[mi], 0, 0, 0);
            }
        }
        // epilogue: silu(gate)*up -> act_f fragment-major
#pragma unroll
        for (int mi = 0; mi < 10; ++mi) {
#pragma unroll
            for (int r = 0; r < 4; ++r) {
                int ml = mh * 160 + mi * 16 + lq * 4 + r;
                int m = tb + ml;
                if (m < npad) {
                    float gv = accg[mi][r], uv = accu[mi][r];
                    float av = gv / (1.f + __expf(-gv)) * uv;
                    int prow = pb + m;
                    size_t o = (size_t)(prow >> 4) * 90112 + (jcol >> 3) * 128
                             + (prow & 15) * 8 + (jcol & 7);
                    actf[o] = (unsigned short)f2bf(av);
                }
            }
        }
    }
}

// ---------------------------------------------------- gemm2: act@w2 --------
// grid = E_*16dt*4seg = 512 blocks. Same barrier-free wave structure:
// wave M=160 x N=32 (2 col frags), K/seg = 1408 (44 steps). Partial sums
// into y[seg]; combine adds 4 segments.
__global__ __launch_bounds__(256, 2) void gemm2_kernel(
    const unsigned short* __restrict__ actf, const int* __restrict__ w2q,
    const float* __restrict__ w2s, const int* __restrict__ cnt,
    const int* __restrict__ basep, float* __restrict__ y)
{
    int bid = blockIdx.x;
    int seg = bid & 3, dt = (bid >> 2) & 15, e = bid >> 6;
    int n = cnt[e];
    if (n <= 0) return;
    int npad = (n + 15) & ~15;
    int pb = basep[e];
    int tid = threadIdx.x, lane = tid & 63, w = tid >> 6;
    int l15 = lane & 15, lq = lane >> 4;
    int colg = w & 1, mh = w >> 1;
    int dcol = dt * 64 + colg * 32 + l15;      // second frag col = dcol + 16

    const char* b00 = (const char*)(w2q + ((size_t)e * 5632 + seg * 1408 + lq * 8) * 1024 + dcol);
    float* yseg = y + (size_t)seg * NPAD_MAX * 1024;

    for (int tb = 0; tb < npad; tb += 320) {
        int aoff[10];
#pragma unroll
        for (int mi = 0; mi < 10; ++mi) {
            int R = tb + mh * 160 + mi * 16;
            R = min(R, npad - 16);
            aoff[mi] = ((pb + R) >> 4) * 180224;
        }
        const char* abase = (const char*)actf + seg * 45056 + lq * 256 + l15 * 16;
        const char* b0 = b00;

        f32x4 acc0[10], acc1[10];
#pragma unroll
        for (int mi = 0; mi < 10; ++mi) {
            acc0[mi] = (f32x4){0.f, 0.f, 0.f, 0.f};
            acc1[mi] = (f32x4){0.f, 0.f, 0.f, 0.f};
        }
        int q0[2][8], q1[2][8];
#pragma unroll
        for (int j = 0; j < 8; ++j) {
            q0[0][j] = *(const int*)(b0 + (size_t)j * 4096);
            q1[0][j] = *(const int*)(b0 + 64 + (size_t)j * 4096);
        }
        b0 += 131072;                           // 32*D_*4
        float s0 = 0.f, s1 = 0.f, o0 = 0.f, o1 = 0.f;

#pragma unroll 4
        for (int t = 0; t < 44; ++t) {
            const int cur = t & 1;
            if ((t & 3) == 0) {
                const float* sp = w2s + ((size_t)e * 44 + seg * 11 + (t >> 2)) * 1024 + dcol;
                s0 = sp[0]; s1 = sp[16];
                o0 = -8.f * s0; o1 = -8.f * s1;
            }
            const char* at = abase + t * 1024;
            bf16x8 a[10];
#pragma unroll
            for (int mi = 0; mi < 10; ++mi)
                a[mi] = *(const bf16x8*)(at + aoff[mi]);
            union { unsigned u[4]; bf16x8 v; } f0, f1;
#pragma unroll
            for (int h = 0; h < 4; ++h) {
                f0.u[h] = pack2bf((float)q0[cur][2*h] * s0 + o0,
                                  (float)q0[cur][2*h+1] * s0 + o0);
                f1.u[h] = pack2bf((float)q1[cur][2*h] * s1 + o1,
                                  (float)q1[cur][2*h+1] * s1 + o1);
            }
            if (t < 43) {
#pragma unroll
                for (int j = 0; j < 8; ++j) {
                    q0[cur ^ 1][j] = *(const int*)(b0 + (size_t)j * 4096);
                    q1[cur ^ 1][j] = *(const int*)(b0 + 64 + (size_t)j * 4096);
                }
                b0 += 131072;
            }
#pragma unroll
            for (int mi = 0; mi < 10; ++mi) {
                acc0[mi] = __builtin_amdgcn_mfma_f32_16x16x32_bf16(a[mi], f0.v, acc0[mi], 0, 0, 0);
                acc1[mi] = __builtin_amdgcn_mfma_f32_16x16x32_bf16(a[mi], f1.v, acc1[mi], 0, 0, 0);
            }
        }
#pragma unroll
        for (int mi = 0; mi < 10; ++mi) {
#pragma unroll
            for (int r = 0; r < 4; ++r) {
                int m = tb + mh * 160 + mi * 16 + lq * 4 + r;
                if (m < n) {
                    float* yr = yseg + (size_t)(pb + m) * 1024;
                    yr[dcol]      = acc0[mi][r];
                    yr[dcol + 16] = acc1[mi][r];
                }
            }
        }
    }
}

// --------------------------------------------------------------- combine ---
__global__ void combine_kernel(const float* __restrict__ y,
                               const int* __restrict__ eslot,
                               const float* __restrict__ tokw,
                               const int* __restrict__ basep,
                               float* __restrict__ out)
{
    int idx = blockIdx.x * blockDim.x + threadIdx.x;
    int t  = idx >> 8;
    int dc = idx & 255;
    int es0 = eslot[t * 2 + 0], es1 = eslot[t * 2 + 1];
    float w0 = tokw[t * 2 + 0], w1 = tokw[t * 2 + 1];
    int p0 = basep[es0 >> 10] + (es0 & 1023);
    int p1 = basep[es1 >> 10] + (es1 & 1023);
    const float4* y4 = (const float4*)y;
    float4 o = (float4){0.f, 0.f, 0.f, 0.f};
#pragma unroll
    for (int seg = 0; seg < 4; ++seg) {
        float4 a = y4[((size_t)seg * NPAD_MAX + p0) * 256 + dc];
        float4 b = y4[((size_t)seg * NPAD_MAX + p1) * 256 + dc];
        o.x += w0 * a.x + w1 * b.x;
        o.y += w0 * a.y + w1 * b.y;
        o.z += w0 * a.z + w1 * b.z;
        o.w += w0 * a.w + w1 * b.w;
    }
    ((float4*)out)[idx] = o;
}

// ---------------------------------------------------------------- launch ---
extern "C" void kernel_launch(void* const* d_in, const int* in_sizes, int n_in,
                              void* d_out, int out_size, void* d_ws, size_t ws_size,
                              hipStream_t stream)
{
    const float* x    = (const float*)d_in[0];
    const float* gate = (const float*)d_in[1];
    const int*   w1q  = (const int*)d_in[2];
    const int*   w2q  = (const int*)d_in[3];
    const float* w1s  = (const float*)d_in[4];
    const float* w2s  = (const float*)d_in[5];
    float* out = (float*)d_out;
    int*   wsi = (int*)d_ws;
    float* wsf = (float*)d_ws;

    int*   cnt   = wsi + WS_CNT;
    int*   basep = wsi + WS_BASEP;
    int*   eslot = wsi + WS_ESLOT;
    float* tokw  = wsf + WS_TOKW;
    int*   etok  = wsi + WS_ETOK;
    unsigned short* actf = (unsigned short*)((char*)d_ws + WS_ACTF_B);
    unsigned short* xgf  = (unsigned short*)((char*)d_ws + WS_XGF_B);
    float*          y    = (float*)((char*)d_ws + WS_Y_B);

    routing_kernel<<<1, 1024, 0, stream>>>(gate, cnt, basep, eslot, tokw, etok);
    gather_cast_kernel<<<E_ * 64, 256, 0, stream>>>(x, cnt, basep, etok, xgf);
    gemm1_kernel<<<E_ * 176, 256, 0, stream>>>(xgf, w1q, w1s, cnt, basep, actf);
    gemm2_kernel<<<E_ * 16 * 4, 256, 0, stream>>>(actf, w2q, w2s, cnt, basep, y);
    combine_kernel<<<(T_ * D_ / 4) / 256, 256, 0, stream>>>(y, eslot, tokw, basep, out);
}